// Round 9
// baseline (378.704 us; speedup 1.0000x reference)
//
#include <hip/hip_runtime.h>
#include <math.h>

#define B 8
#define C 64
#define HW 96
#define NWV 36864            // per-variant weight elems: 9 taps * 64 co * 64 ci

typedef __attribute__((ext_vector_type(8)))  short short8;
typedef __attribute__((ext_vector_type(16))) float floatx16;

__device__ __forceinline__ unsigned short f2bf(float f) {
    unsigned int u = __float_as_uint(f);
    unsigned int r = (u + 0x7fffu + ((u >> 16) & 1u)) >> 16;
    return (unsigned short)r;
}

// tap rotation: effective kernel for rotation k is K'[i,j] = r^k(K)[i,j], r(K)[i,j]=K[2-j,i]
__device__ __forceinline__ void rotmap(int k, int ta, int tb, int& sa, int& sb) {
    switch (k) {
        case 0: sa = ta;     sb = tb;     break;
        case 1: sa = 2 - tb; sb = ta;     break;
        case 2: sa = 2 - ta; sb = 2 - tb; break;
        default: sa = tb;    sb = 2 - ta; break;
    }
}

// ---------------- prep kernels ----------------
// Frag-contiguous weight layout per variant:
//   idx = (((tap*4 + ks)*2 + cf)*64 + lane)*8 + j
//   co = cf*32 + (lane&31); ci = ks*16 + (lane>>5)*8 + j
__global__ void prep_w(const float* __restrict__ dcn_w, const float* __restrict__ c2w,
                       const float* __restrict__ c3w,
                       const float* __restrict__ gamma, const float* __restrict__ var_,
                       unsigned short* __restrict__ Wall) {
    int idx = blockIdx.x * 256 + threadIdx.x;
    if (idx >= 16 * NWV) return;
    int v = idx / NWV, rem = idx % NWV;
    int tap  = rem >> 12;
    int w12  = rem & 4095;
    int ks   = w12 >> 10;
    int cf   = (w12 >> 9) & 1;
    int lane = (w12 >> 3) & 63;
    int j    = w12 & 7;
    int co = cf * 32 + (lane & 31);
    int ci = ks * 16 + (lane >> 5) * 8 + j;
    int ta = tap / 3, tb = tap % 3;
    const float* src; int k, srcci, l;
    if (v < 8)       { k = v & 3;  srcci = (ci + 8 * v) & 63; src = dcn_w; l = 0; }
    else if (v < 12) { k = v - 8;  srcci = ci; src = c2w; l = 1; }
    else             { k = v - 12; srcci = ci; src = c3w; l = 2; }
    int sa, sb; rotmap(k, ta, tb, sa, sb);
    float s = gamma[l * 64 + co] * rsqrtf(var_[l * 64 + co] + 1e-5f);
    Wall[idx] = f2bf(src[((co * 64 + srcci) * 3 + sa) * 3 + sb] * s);
}

__global__ void prep_bias(const float* __restrict__ dcn_b, const float* __restrict__ c2b,
                          const float* __restrict__ c3b,
                          const float* __restrict__ gamma, const float* __restrict__ beta,
                          const float* __restrict__ mean, const float* __restrict__ var_,
                          float* __restrict__ biasg) {
    int t = threadIdx.x;
    if (t < 192) {
        int l = t >> 6, c = t & 63;
        const float* cb = (l == 0) ? dcn_b : ((l == 1) ? c2b : c3b);
        float s = gamma[l * 64 + c] * rsqrtf(var_[l * 64 + c] + 1e-5f);
        biasg[t] = cb[c] * s + beta[l * 64 + c] - mean[l * 64 + c] * s;
    }
}

// NCHW fp32 -> NHWC bf16.
__global__ __launch_bounds__(256) void prep_x(const float* __restrict__ in,
                                              unsigned short* __restrict__ out) {
    __shared__ float row[64 * 97];
    int by = blockIdx.x;
    int b = by / 96, y = by % 96;
    int t = threadIdx.x;
    for (int e = t; e < 6144; e += 256) {
        int c = e / 96, x = e - c * 96;
        row[c * 97 + x] = in[(((size_t)(b * 64 + c) * 96 + y) * 96) + x];
    }
    __syncthreads();
    for (int e = t; e < 6144; e += 256) {
        int x = e >> 6, c = e & 63;
        out[(((size_t)(b * 96 + y) * 96 + x) << 6) + c] = f2bf(row[c * 97 + x]);
    }
}

// Zero the 4-wide border ring of even-branch 104x104 frames.
__global__ __launch_bounds__(256) void border_clear(unsigned short* __restrict__ buf1) {
    int idx = blockIdx.y;
    int br = (idx >> 3) * 2, b = idx & 7;
    int z = br * 8 + b;
    int i = blockIdx.x * 32 + (threadIdx.x >> 3);
    int g = threadIdx.x & 7;
    int r, c;
    if (i < 416)      { r = i / 104;              c = i % 104; }
    else if (i < 832) { int j = i - 416; r = 100 + j / 104; c = j % 104; }
    else              { int j = i - 832; r = 4 + (j >> 3); int c8 = j & 7;
                        c = (c8 < 4) ? c8 : 92 + c8; }
    uint4 zero = make_uint4(0u, 0u, 0u, 0u);
    *(uint4*)(buf1 + (size_t)z * (104 * 104 * 64) + ((size_t)(r * 104 + c) << 6) + (g << 3)) = zero;
}

// ---------------- conv1: all 8 branches -> framed buf1 (104x104, NHWC bf16) ----------------
__global__ __launch_bounds__(256, 2) void conv1_k(
    const unsigned short* __restrict__ xhwc, unsigned short* __restrict__ buf1,
    const unsigned short* __restrict__ Wall, const float* __restrict__ biasg) {

    __shared__ __align__(16) unsigned short xt[10 * 34 * 64];   // 43,520 B

    int z = blockIdx.z, br = z >> 3, b = z & 7, odd = br & 1;
    int fy0 = blockIdx.y * 8, fx0 = blockIdx.x * 32;
    int t = threadIdx.x, lane = t & 63, wv = t >> 6;
    int n = lane & 31, kq = lane >> 5;

    const unsigned short* xb = xhwc + ((size_t)b * 96 * 96 << 6);
    const short8* Ag = (const short8*)(Wall + (size_t)br * NWV);

    for (int e = t; e < 2720; e += 256) {
        int p = e >> 3, g = e & 7;
        int yy = p / 34, xx = p - yy * 34;
        int gy = fy0 - 5 + yy, gx = fx0 - 5 + xx;
        uint4 v = make_uint4(0u, 0u, 0u, 0u);
        if ((unsigned)gy < 96u && (unsigned)gx < 96u)
            v = *(const uint4*)(xb + ((size_t)(gy * 96 + gx) << 6) + (g << 3));
        *(uint4*)(xt + (p << 6) + ((g ^ (xx & 7)) << 3)) = v;
    }
    __syncthreads();

    floatx16 acc[2][2];
#pragma unroll
    for (int cf = 0; cf < 2; cf++)
#pragma unroll
        for (int pf = 0; pf < 2; pf++)
#pragma unroll
            for (int i = 0; i < 16; i++) acc[cf][pf][i] = 0.f;

#pragma unroll
    for (int ks = 0; ks < 4; ks++) {
#pragma unroll
        for (int tb = 0; tb < 3; tb++) {
            short8 a[3][2];
#pragma unroll
            for (int ta = 0; ta < 3; ta++)
#pragma unroll
                for (int cf = 0; cf < 2; cf++)
                    a[ta][cf] = Ag[(((ta * 3 + tb) * 4 + ks) * 2 + cf) * 64 + lane];
            int xx = n + tb;
            int g = ((ks * 2 + kq) ^ (xx & 7)) << 3;
            short8 bf[4];
#pragma unroll
            for (int rr = 0; rr < 4; rr++) {
                int p = (2 * wv + rr) * 34 + xx;
                bf[rr] = *(const short8*)(xt + (p << 6) + g);
            }
#pragma unroll
            for (int ta = 0; ta < 3; ta++)
#pragma unroll
                for (int pf = 0; pf < 2; pf++) {
                    int rr = pf + ta;
                    acc[0][pf] = __builtin_amdgcn_mfma_f32_32x32x16_bf16(a[ta][0], bf[rr], acc[0][pf], 0, 0, 0);
                    acc[1][pf] = __builtin_amdgcn_mfma_f32_32x32x16_bf16(a[ta][1], bf[rr], acc[1][pf], 0, 0, 0);
                }
        }
    }

    float4 bv[2][4];
#pragma unroll
    for (int cf = 0; cf < 2; cf++)
#pragma unroll
        for (int rb = 0; rb < 4; rb++)
            bv[cf][rb] = *(const float4*)(biasg + 32 * cf + 8 * rb + 4 * kq);

    __syncthreads();
#pragma unroll
    for (int pf = 0; pf < 2; pf++) {
        int pq = (2 * wv + pf) * 32 + n;
        int key = (pq & 7) << 1;
#pragma unroll
        for (int cf = 0; cf < 2; cf++)
#pragma unroll
            for (int rb = 0; rb < 4; rb++) {
                int u = kq + 2 * rb + 8 * cf;
                float v0 = fmaxf(acc[cf][pf][rb * 4 + 0] + bv[cf][rb].x, 0.f);
                float v1 = fmaxf(acc[cf][pf][rb * 4 + 1] + bv[cf][rb].y, 0.f);
                float v2 = fmaxf(acc[cf][pf][rb * 4 + 2] + bv[cf][rb].z, 0.f);
                float v3 = fmaxf(acc[cf][pf][rb * 4 + 3] + bv[cf][rb].w, 0.f);
                uint2 pk = make_uint2((unsigned)f2bf(v0) | ((unsigned)f2bf(v1) << 16),
                                      (unsigned)f2bf(v2) | ((unsigned)f2bf(v3) << 16));
                *(uint2*)((char*)xt + pq * 128 + ((u ^ key) << 3)) = pk;
            }
    }
    __syncthreads();

    unsigned short* fb = buf1 + (size_t)z * (104 * 104 * 64);
    int lo = odd ? 0 : 4, hi = odd ? 104 : 100;
    for (int e = t; e < 2048; e += 256) {
        int px = e >> 3, g = e & 7;
        int key = (px & 7) << 1;
        uint4 v = *(const uint4*)((const char*)xt + px * 128 + (((2 * g) ^ key) << 3));
        int lr = px >> 5, nn = px & 31;
        int f = fy0 + lr, fc = fx0 + nn;
        if (f >= lo && f < hi && fc >= lo && fc < hi)
            *(uint4*)(fb + ((size_t)(f * 104 + fc) << 6) + (g << 3)) = v;
    }
}

// ---------------- fused conv2+conv3 -> maxbuf ----------------
// Grid 3x12x64, 512 thr (8 waves). conv3-out tile 8x32; conv2-out 12x36 in LDS.
// Plane layouts (16B records, conflict-free & aligned):
//   xs: 2 planes (8ci) x 640 px (16x40) x 16B = 20,480 B; 4 staging rounds of 16 ci.
//   c2out: 8 planes (8co) x 432 px (12x36) x 16B = 55,296 B.
// acc2 peak 64 AGPR (jj<2, cf<2); acc3 32 reuses. Total regs ~140 < 256 -> no spill.
__global__ __launch_bounds__(512, 2) void conv23_k(
    const unsigned short* __restrict__ buf1, float* __restrict__ maxb,
    const unsigned short* __restrict__ Wall, const float* __restrict__ biasg) {

    __shared__ __align__(16) unsigned short xs[2 * 5120];      // 20,480 B
    __shared__ __align__(16) unsigned short c2out[8 * 3456];   // 55,296 B

    int z = blockIdx.z, br = z >> 3, odd = br & 1;
    int oy0 = blockIdx.y * 8, ox0 = blockIdx.x * 32;
    int t = threadIdx.x, lane = t & 63, wv = t >> 6;
    int n = lane & 31, kq = lane >> 5;

    const unsigned short* fb = buf1 + (size_t)z * (104 * 104 * 64);
    const short8* A2 = (const short8*)(Wall + (size_t)(8  + (br & 3)) * NWV);
    const short8* A3 = (const short8*)(Wall + (size_t)(12 + (br & 3)) * NWV);

    // per-wave conv2-out pixel coords (q-linear over 12x36, clamped)
    int q_[2], row2_[2], col2_[2];
#pragma unroll
    for (int jj = 0; jj < 2; jj++) {
        int q = 64 * wv + 32 * jj + n;
        q_[jj] = q;
        int qc = (q < 432) ? q : 431;
        int r2 = qc / 36;
        row2_[jj] = r2;
        col2_[jj] = qc - 36 * r2;
    }

    // staging: 1280 uint4 per 16-ci stage (640 px x 2 groups); e = t + 512*k2, k2<3
    int sp_off[3], sp_lds[3]; bool sp_on[3];
#pragma unroll
    for (int k2 = 0; k2 < 3; k2++) {
        int e = t + k2 * 512;
        sp_on[k2] = e < 1280;
        int p = e >> 1, g = e & 1;
        if (!sp_on[k2]) { p = 0; g = 0; }
        int yy = p / 40, xx = p - yy * 40;
        sp_off[k2] = (((oy0 + yy) * 104 + ox0 + xx) << 6) + (g << 3);
        sp_lds[k2] = g * 5120 + (p << 3);
    }

    uint4 ld[3];
#pragma unroll
    for (int k2 = 0; k2 < 3; k2++)
        if (sp_on[k2]) ld[k2] = *(const uint4*)(fb + sp_off[k2]);

    floatx16 acc2[2][2];
#pragma unroll
    for (int jj = 0; jj < 2; jj++)
#pragma unroll
        for (int cf = 0; cf < 2; cf++)
#pragma unroll
            for (int i = 0; i < 16; i++) acc2[jj][cf][i] = 0.f;

    for (int ks = 0; ks < 4; ks++) {
        if (ks) __syncthreads();          // prior-stage readers done
#pragma unroll
        for (int k2 = 0; k2 < 3; k2++)
            if (sp_on[k2]) *(uint4*)(xs + sp_lds[k2]) = ld[k2];
        if (ks < 3) {
#pragma unroll
            for (int k2 = 0; k2 < 3; k2++)
                if (sp_on[k2]) ld[k2] = *(const uint4*)(fb + sp_off[k2] + ((ks + 1) << 4));
        }
        __syncthreads();                  // xs ready

#pragma unroll
        for (int tb = 0; tb < 3; tb++) {
            short8 a[3][2];
#pragma unroll
            for (int ta = 0; ta < 3; ta++)
#pragma unroll
                for (int cf = 0; cf < 2; cf++)
                    a[ta][cf] = A2[(((ta * 3 + tb) * 4 + ks) * 2 + cf) * 64 + lane];
            int uoff = kq * 5120;
#pragma unroll
            for (int jj = 0; jj < 2; jj++) {
                int colx = col2_[jj] + 2 * tb;
#pragma unroll
                for (int ta = 0; ta < 3; ta++) {
                    int p = (row2_[jj] + 2 * ta) * 40 + colx;
                    short8 bfr = *(const short8*)(xs + uoff + (p << 3));
                    acc2[jj][0] = __builtin_amdgcn_mfma_f32_32x32x16_bf16(a[ta][0], bfr, acc2[jj][0], 0, 0, 0);
                    acc2[jj][1] = __builtin_amdgcn_mfma_f32_32x32x16_bf16(a[ta][1], bfr, acc2[jj][1], 0, 0, 0);
                }
            }
        }
    }

    // ---- conv2 epilogue -> c2out planes (bias+relu, zero-mask even-parity borders) ----
    int rlo2 = (!odd && oy0 == 0)  ? 2  : 0;
    int rhi2 = (!odd && oy0 == 88) ? 10 : 12;
    int clo2 = (!odd && ox0 == 0)  ? 2  : 0;
    int chi2 = (!odd && ox0 == 64) ? 34 : 36;

#pragma unroll
    for (int jj = 0; jj < 2; jj++) {
        if (q_[jj] < 432) {
            bool valid = (row2_[jj] >= rlo2) && (row2_[jj] < rhi2) &&
                         (col2_[jj] >= clo2) && (col2_[jj] < chi2);
#pragma unroll
            for (int cf = 0; cf < 2; cf++)
#pragma unroll
                for (int rb = 0; rb < 4; rb++) {
                    float v0 = 0.f, v1 = 0.f, v2 = 0.f, v3 = 0.f;
                    if (valid) {
                        float4 bb = *(const float4*)(biasg + 64 + 32 * cf + 8 * rb + 4 * kq);
                        v0 = fmaxf(acc2[jj][cf][rb * 4 + 0] + bb.x, 0.f);
                        v1 = fmaxf(acc2[jj][cf][rb * 4 + 1] + bb.y, 0.f);
                        v2 = fmaxf(acc2[jj][cf][rb * 4 + 2] + bb.z, 0.f);
                        v3 = fmaxf(acc2[jj][cf][rb * 4 + 3] + bb.w, 0.f);
                    }
                    uint2 pk = make_uint2((unsigned)f2bf(v0) | ((unsigned)f2bf(v1) << 16),
                                          (unsigned)f2bf(v2) | ((unsigned)f2bf(v3) << 16));
                    // plane u = 4cf+rb, record offset kq*4 shorts
                    *(uint2*)(c2out + (4 * cf + rb) * 3456 + (q_[jj] << 3) + 4 * kq) = pk;
                }
        }
    }
    __syncthreads();

    // ---- conv3 from c2out planes; wave owns out row wv x 32 cols ----
    floatx16 acc3[2];
#pragma unroll
    for (int cf = 0; cf < 2; cf++)
#pragma unroll
        for (int i = 0; i < 16; i++) acc3[cf][i] = 0.f;

#pragma unroll
    for (int ks = 0; ks < 4; ks++) {
#pragma unroll
        for (int tb = 0; tb < 3; tb++) {
            short8 a[3][2];
#pragma unroll
            for (int ta = 0; ta < 3; ta++)
#pragma unroll
                for (int cf = 0; cf < 2; cf++)
                    a[ta][cf] = A3[(((ta * 3 + tb) * 4 + ks) * 2 + cf) * 64 + lane];
            int col = n + 2 * tb;
            int uoff = (2 * ks + kq) * 3456;   // ci-chunk plane
#pragma unroll
            for (int ta = 0; ta < 3; ta++) {
                int p = (wv + 2 * ta) * 36 + col;
                short8 bfr = *(const short8*)(c2out + uoff + (p << 3));
                acc3[0] = __builtin_amdgcn_mfma_f32_32x32x16_bf16(a[ta][0], bfr, acc3[0], 0, 0, 0);
                acc3[1] = __builtin_amdgcn_mfma_f32_32x32x16_bf16(a[ta][1], bfr, acc3[1], 0, 0, 0);
            }
        }
    }

    // epilogue: bias + relu + max over 64 co -> maxb
    {
        float m = 0.f;
#pragma unroll
        for (int cf = 0; cf < 2; cf++)
#pragma unroll
            for (int rb = 0; rb < 4; rb++) {
                float4 bb = *(const float4*)(biasg + 128 + 32 * cf + 8 * rb + 4 * kq);
                m = fmaxf(m, acc3[cf][rb * 4 + 0] + bb.x);
                m = fmaxf(m, acc3[cf][rb * 4 + 1] + bb.y);
                m = fmaxf(m, acc3[cf][rb * 4 + 2] + bb.z);
                m = fmaxf(m, acc3[cf][rb * 4 + 3] + bb.w);
            }
        m = fmaxf(m, 0.f);
        m = fmaxf(m, __shfl_xor(m, 32, 64));
        if (lane < 32)
            maxb[((size_t)z * 96 + oy0 + wv) * 96 + ox0 + n] = m;
    }
}

__global__ void final_k(const float* __restrict__ maxb, float* __restrict__ out) {
    int i = blockIdx.x * 256 + threadIdx.x;
    if (i < B * HW * HW) {
        int b = i / 9216, yx = i - b * 9216;
        float m = 0.f;
#pragma unroll
        for (int br = 0; br < 8; br++)
            m = fmaxf(m, maxb[((size_t)(br * 8 + b)) * 9216 + yx]);
        float v = 1.f / (1.f + expf(-m));
        out[i] = fminf(fmaxf(v, 1e-4f), 1.f - 1e-4f);
    }
}

// ---------------- launch ----------------

extern "C" void kernel_launch(void* const* d_in, const int* in_sizes, int n_in,
                              void* d_out, int out_size, void* d_ws, size_t ws_size,
                              hipStream_t stream) {
    const float* x     = (const float*)d_in[0];
    const float* dcn_w = (const float*)d_in[2];
    const float* dcn_b = (const float*)d_in[3];
    const float* c2w   = (const float*)d_in[4];
    const float* c2b   = (const float*)d_in[5];
    const float* c3w   = (const float*)d_in[6];
    const float* c3b   = (const float*)d_in[7];
    const float* gamma = (const float*)d_in[8];
    const float* beta  = (const float*)d_in[9];
    const float* mean  = (const float*)d_in[10];
    const float* var_  = (const float*)d_in[11];

    char* ws = (char*)d_ws;
    unsigned short* Wall = (unsigned short*)ws;                       // 1.18 MB
    size_t off = (size_t)16 * NWV * 2;
    float* biasg = (float*)(ws + off);            off += 1024;
    float* maxb  = (float*)(ws + off);            off += (size_t)64 * 9216 * 4;        // 2.36 MB
    unsigned short* xhwc = (unsigned short*)(ws + off); off += (size_t)B * 9216 * 64 * 2;    // 9.4 MB
    unsigned short* buf1 = (unsigned short*)(ws + off);                                 // 88.6 MB framed

    prep_w<<<(16 * NWV + 255) / 256, 256, 0, stream>>>(dcn_w, c2w, c3w, gamma, var_, Wall);
    prep_bias<<<1, 256, 0, stream>>>(dcn_b, c2b, c3b, gamma, beta, mean, var_, biasg);
    prep_x<<<B * 96, 256, 0, stream>>>(x, xhwc);
    border_clear<<<dim3(50, 32), 256, 0, stream>>>(buf1);

    dim3 g1(4, 13, 64);
    conv1_k<<<g1, 256, 0, stream>>>(xhwc, buf1, Wall, biasg);

    dim3 g23(3, 12, 64);
    conv23_k<<<g23, 512, 0, stream>>>(buf1, maxb, Wall, biasg);

    final_k<<<(B * HW * HW + 255) / 256, 256, 0, stream>>>(maxb, (float*)d_out);
}

// Round 10
// 338.093 us; speedup vs baseline: 1.1201x; 1.1201x over previous
//
#include <hip/hip_runtime.h>
#include <math.h>

#define B 8
#define C 64
#define HW 96
#define NWV 36864            // per-variant weight elems: 9 taps * 64 co * 64 ci

typedef __attribute__((ext_vector_type(8)))  short short8;
typedef __attribute__((ext_vector_type(16))) float floatx16;

__device__ __forceinline__ unsigned short f2bf(float f) {
    unsigned int u = __float_as_uint(f);
    unsigned int r = (u + 0x7fffu + ((u >> 16) & 1u)) >> 16;
    return (unsigned short)r;
}

// tap rotation: effective kernel for rotation k is K'[i,j] = r^k(K)[i,j], r(K)[i,j]=K[2-j,i]
__device__ __forceinline__ void rotmap(int k, int ta, int tb, int& sa, int& sb) {
    switch (k) {
        case 0: sa = ta;     sb = tb;     break;
        case 1: sa = 2 - tb; sb = ta;     break;
        case 2: sa = 2 - ta; sb = 2 - tb; break;
        default: sa = tb;    sb = 2 - ta; break;
    }
}

// ---------------- prep kernels ----------------
// Frag-contiguous weight layout per variant:
//   idx = (((tap*4 + ks)*2 + cf)*64 + lane)*8 + j
//   co = cf*32 + (lane&31); ci = ks*16 + (lane>>5)*8 + j
__global__ void prep_w(const float* __restrict__ dcn_w, const float* __restrict__ c2w,
                       const float* __restrict__ c3w,
                       const float* __restrict__ gamma, const float* __restrict__ var_,
                       unsigned short* __restrict__ Wall) {
    int idx = blockIdx.x * 256 + threadIdx.x;
    if (idx >= 16 * NWV) return;
    int v = idx / NWV, rem = idx % NWV;
    int tap  = rem >> 12;
    int w12  = rem & 4095;
    int ks   = w12 >> 10;
    int cf   = (w12 >> 9) & 1;
    int lane = (w12 >> 3) & 63;
    int j    = w12 & 7;
    int co = cf * 32 + (lane & 31);
    int ci = ks * 16 + (lane >> 5) * 8 + j;
    int ta = tap / 3, tb = tap % 3;
    const float* src; int k, srcci, l;
    if (v < 8)       { k = v & 3;  srcci = (ci + 8 * v) & 63; src = dcn_w; l = 0; }
    else if (v < 12) { k = v - 8;  srcci = ci; src = c2w; l = 1; }
    else             { k = v - 12; srcci = ci; src = c3w; l = 2; }
    int sa, sb; rotmap(k, ta, tb, sa, sb);
    float s = gamma[l * 64 + co] * rsqrtf(var_[l * 64 + co] + 1e-5f);
    Wall[idx] = f2bf(src[((co * 64 + srcci) * 3 + sa) * 3 + sb] * s);
}

__global__ void prep_bias(const float* __restrict__ dcn_b, const float* __restrict__ c2b,
                          const float* __restrict__ c3b,
                          const float* __restrict__ gamma, const float* __restrict__ beta,
                          const float* __restrict__ mean, const float* __restrict__ var_,
                          float* __restrict__ biasg) {
    int t = threadIdx.x;
    if (t < 192) {
        int l = t >> 6, c = t & 63;
        const float* cb = (l == 0) ? dcn_b : ((l == 1) ? c2b : c3b);
        float s = gamma[l * 64 + c] * rsqrtf(var_[l * 64 + c] + 1e-5f);
        biasg[t] = cb[c] * s + beta[l * 64 + c] - mean[l * 64 + c] * s;
    }
}

// NCHW fp32 -> NHWC bf16.
__global__ __launch_bounds__(256) void prep_x(const float* __restrict__ in,
                                              unsigned short* __restrict__ out) {
    __shared__ float row[64 * 97];
    int by = blockIdx.x;
    int b = by / 96, y = by % 96;
    int t = threadIdx.x;
    for (int e = t; e < 6144; e += 256) {
        int c = e / 96, x = e - c * 96;
        row[c * 97 + x] = in[(((size_t)(b * 64 + c) * 96 + y) * 96) + x];
    }
    __syncthreads();
    for (int e = t; e < 6144; e += 256) {
        int x = e >> 6, c = e & 63;
        out[(((size_t)(b * 96 + y) * 96 + x) << 6) + c] = f2bf(row[c * 97 + x]);
    }
}

// Zero the 4-wide border ring of even-branch 104x104 frames.
__global__ __launch_bounds__(256) void border_clear(unsigned short* __restrict__ buf1) {
    int idx = blockIdx.y;
    int br = (idx >> 3) * 2, b = idx & 7;
    int z = br * 8 + b;
    int i = blockIdx.x * 32 + (threadIdx.x >> 3);
    int g = threadIdx.x & 7;
    int r, c;
    if (i < 416)      { r = i / 104;              c = i % 104; }
    else if (i < 832) { int j = i - 416; r = 100 + j / 104; c = j % 104; }
    else              { int j = i - 832; r = 4 + (j >> 3); int c8 = j & 7;
                        c = (c8 < 4) ? c8 : 92 + c8; }
    uint4 zero = make_uint4(0u, 0u, 0u, 0u);
    *(uint4*)(buf1 + (size_t)z * (104 * 104 * 64) + ((size_t)(r * 104 + c) << 6) + (g << 3)) = zero;
}

// ---------------- conv1: all 8 branches -> framed buf1 (104x104, NHWC bf16) ----------------
// 512 thr (8 waves), tile 16 rows x 32 cols x 64 co. Input 18x34x64ci staged once (78.3KB).
// Wave w owns out rows {2w, 2w+1}. Epilogue transposes through LDS -> contiguous stores.
__global__ __launch_bounds__(512, 1) void conv1_k(
    const unsigned short* __restrict__ xhwc, unsigned short* __restrict__ buf1,
    const unsigned short* __restrict__ Wall, const float* __restrict__ biasg) {

    __shared__ __align__(16) unsigned short xt[612 * 64];   // 78,336 B

    int z = blockIdx.z, br = z >> 3, b = z & 7, odd = br & 1;
    int fy0 = blockIdx.y * 16, fx0 = blockIdx.x * 32;
    int t = threadIdx.x, lane = t & 63, wv = t >> 6;
    int n = lane & 31, kq = lane >> 5;

    const unsigned short* xb = xhwc + ((size_t)b * 96 * 96 << 6);
    const short8* Ag = (const short8*)(Wall + (size_t)br * NWV);

    // stage x: tile rows fy0-5..+18, cols fx0-5..+34, zero OOB
    for (int e = t; e < 4896; e += 512) {
        int p = e >> 3, g = e & 7;
        int yy = p / 34, xx = p - yy * 34;
        int gy = fy0 - 5 + yy, gx = fx0 - 5 + xx;
        uint4 v = make_uint4(0u, 0u, 0u, 0u);
        if ((unsigned)gy < 96u && (unsigned)gx < 96u)
            v = *(const uint4*)(xb + ((size_t)(gy * 96 + gx) << 6) + (g << 3));
        *(uint4*)(xt + (p << 6) + ((g ^ (xx & 7)) << 3)) = v;
    }
    __syncthreads();

    floatx16 acc[2][2];
#pragma unroll
    for (int cf = 0; cf < 2; cf++)
#pragma unroll
        for (int pf = 0; pf < 2; pf++)
#pragma unroll
            for (int i = 0; i < 16; i++) acc[cf][pf][i] = 0.f;

#pragma unroll
    for (int ks = 0; ks < 4; ks++) {
#pragma unroll
        for (int tb = 0; tb < 3; tb++) {
            short8 a[3][2];
#pragma unroll
            for (int ta = 0; ta < 3; ta++)
#pragma unroll
                for (int cf = 0; cf < 2; cf++)
                    a[ta][cf] = Ag[(((ta * 3 + tb) * 4 + ks) * 2 + cf) * 64 + lane];
            int xx = n + tb;
            int g = ((ks * 2 + kq) ^ (xx & 7)) << 3;
            short8 bf[4];
#pragma unroll
            for (int rr = 0; rr < 4; rr++) {
                int p = (2 * wv + rr) * 34 + xx;
                bf[rr] = *(const short8*)(xt + (p << 6) + g);
            }
#pragma unroll
            for (int ta = 0; ta < 3; ta++)
#pragma unroll
                for (int pf = 0; pf < 2; pf++) {
                    int rr = pf + ta;
                    acc[0][pf] = __builtin_amdgcn_mfma_f32_32x32x16_bf16(a[ta][0], bf[rr], acc[0][pf], 0, 0, 0);
                    acc[1][pf] = __builtin_amdgcn_mfma_f32_32x32x16_bf16(a[ta][1], bf[rr], acc[1][pf], 0, 0, 0);
                }
        }
    }

    float4 bv[2][4];
#pragma unroll
    for (int cf = 0; cf < 2; cf++)
#pragma unroll
        for (int rb = 0; rb < 4; rb++)
            bv[cf][rb] = *(const float4*)(biasg + 32 * cf + 8 * rb + 4 * kq);

    __syncthreads();   // xt reads done; reuse as transpose buffer (512 px * 128 B)
#pragma unroll
    for (int pf = 0; pf < 2; pf++) {
        int pq = (2 * wv + pf) * 32 + n;
        int key = (pq & 7) << 1;
#pragma unroll
        for (int cf = 0; cf < 2; cf++)
#pragma unroll
            for (int rb = 0; rb < 4; rb++) {
                int u = kq + 2 * rb + 8 * cf;
                float v0 = fmaxf(acc[cf][pf][rb * 4 + 0] + bv[cf][rb].x, 0.f);
                float v1 = fmaxf(acc[cf][pf][rb * 4 + 1] + bv[cf][rb].y, 0.f);
                float v2 = fmaxf(acc[cf][pf][rb * 4 + 2] + bv[cf][rb].z, 0.f);
                float v3 = fmaxf(acc[cf][pf][rb * 4 + 3] + bv[cf][rb].w, 0.f);
                uint2 pk = make_uint2((unsigned)f2bf(v0) | ((unsigned)f2bf(v1) << 16),
                                      (unsigned)f2bf(v2) | ((unsigned)f2bf(v3) << 16));
                *(uint2*)((char*)xt + pq * 128 + ((u ^ key) << 3)) = pk;
            }
    }
    __syncthreads();

    unsigned short* fb = buf1 + (size_t)z * (104 * 104 * 64);
    int lo = odd ? 0 : 4, hi = odd ? 104 : 100;
    for (int e = t; e < 4096; e += 512) {
        int px = e >> 3, g = e & 7;
        int key = (px & 7) << 1;
        uint4 v = *(const uint4*)((const char*)xt + px * 128 + (((2 * g) ^ key) << 3));
        int lr = px >> 5, nn = px & 31;
        int f = fy0 + lr, fc = fx0 + nn;
        if (f >= lo && f < hi && fc >= lo && fc < hi)
            *(uint4*)(fb + ((size_t)(f * 104 + fc) << 6) + (g << 3)) = v;
    }
}

// ---------------- fused conv2+conv3 -> maxbuf (r5 structure, conflict-free c2out) ----------------
// Grid 3x6x64, 512 thr (8 waves). conv3-out tile 16x32. conv2-out 20x36x64 in LDS
// at pixel stride 68 shorts (34 dw, gcd 2 -> free). xs: 24x40 px, 32-ci stages,
// stride 32 shorts with xor swizzle (r5 layout). Stage 1 register-prefetched.
__global__ __launch_bounds__(512, 1) void conv23_k(
    const unsigned short* __restrict__ buf1, float* __restrict__ maxb,
    const unsigned short* __restrict__ Wall, const float* __restrict__ biasg) {

    __shared__ __align__(16) unsigned short xs[960 * 32];      // 61,440 B
    __shared__ __align__(16) unsigned short c2out[720 * 68];   // 97,920 B

    int z = blockIdx.z, br = z >> 3, odd = br & 1;
    int oy0 = blockIdx.y * 16, ox0 = blockIdx.x * 32;
    int t = threadIdx.x, lane = t & 63, wv = t >> 6;
    int n = lane & 31, kq = lane >> 5;

    const unsigned short* fb = buf1 + (size_t)z * (104 * 104 * 64);
    const short8* A2 = (const short8*)(Wall + (size_t)(8  + (br & 3)) * NWV);
    const short8* A3 = (const short8*)(Wall + (size_t)(12 + (br & 3)) * NWV);

    // ---- P1: stage ci 0..31 ----
    for (int e = t; e < 3840; e += 512) {
        int p = e >> 2, g = e & 3;
        int yy = p / 40, xx = p - yy * 40;
        uint4 v = *(const uint4*)(fb + ((size_t)((oy0 + yy) * 104 + ox0 + xx) << 6) + (g << 3));
        *(uint4*)(xs + (p << 5) + ((g ^ (xx & 3)) << 3)) = v;
    }
    __syncthreads();

    // prefetch ci 32..63 into registers (overlaps stage-0 compute)
    uint4 pfv[8];
#pragma unroll
    for (int k = 0; k < 8; k++) {
        int e = t + k * 512;
        if (e < 3840) {
            int p = e >> 2, g = e & 3;
            int yy = p / 40, xx = p - yy * 40;
            pfv[k] = *(const uint4*)(fb + ((size_t)((oy0 + yy) * 104 + ox0 + xx) << 6) + 32 + (g << 3));
        }
    }

    // per-wave conv2-out pixel coords (3 chunks of 32, q-linear over 20x36, clamped)
    int q_[3], row2_[3], col2_[3];
#pragma unroll
    for (int jj = 0; jj < 3; jj++) {
        int q = 96 * wv + 32 * jj + n;
        q_[jj] = q;
        int qc = (q < 720) ? q : 719;
        int r2 = qc / 36;
        row2_[jj] = r2;
        col2_[jj] = qc - 36 * r2;
    }

    floatx16 acc2[3][2];   // [jj][cf]
#pragma unroll
    for (int jj = 0; jj < 3; jj++)
#pragma unroll
        for (int cf = 0; cf < 2; cf++)
#pragma unroll
            for (int i = 0; i < 16; i++) acc2[jj][cf][i] = 0.f;

    // ---- conv2 K-halves ----
#pragma unroll
    for (int s = 0; s < 2; s++) {
        if (s == 1) {
            __syncthreads();
#pragma unroll
            for (int k = 0; k < 8; k++) {
                int e = t + k * 512;
                if (e < 3840) {
                    int p = e >> 2, g = e & 3;
                    int xx2 = p - (p / 40) * 40;
                    *(uint4*)(xs + (p << 5) + ((g ^ (xx2 & 3)) << 3)) = pfv[k];
                }
            }
            __syncthreads();
        }
#pragma unroll
        for (int kl = 0; kl < 2; kl++) {
            int ks = s * 2 + kl;
#pragma unroll
            for (int tb = 0; tb < 3; tb++) {
                short8 a[3][2];
#pragma unroll
                for (int ta = 0; ta < 3; ta++)
#pragma unroll
                    for (int cf = 0; cf < 2; cf++)
                        a[ta][cf] = A2[(((ta * 3 + tb) * 4 + ks) * 2 + cf) * 64 + lane];
#pragma unroll
                for (int jj = 0; jj < 3; jj++) {
                    int colx = col2_[jj] + 2 * tb;
                    int gsw = ((kl * 2 + kq) ^ (colx & 3)) << 3;
#pragma unroll
                    for (int ta = 0; ta < 3; ta++) {
                        int p = (row2_[jj] + 2 * ta) * 40 + colx;
                        short8 bfr = *(const short8*)(xs + (p << 5) + gsw);
                        acc2[jj][0] = __builtin_amdgcn_mfma_f32_32x32x16_bf16(a[ta][0], bfr, acc2[jj][0], 0, 0, 0);
                        acc2[jj][1] = __builtin_amdgcn_mfma_f32_32x32x16_bf16(a[ta][1], bfr, acc2[jj][1], 0, 0, 0);
                    }
                }
            }
        }
    }

    // ---- conv2 epilogue -> c2out (bias+relu, zero-mask even-parity borders) ----
    int rlo2 = (!odd && oy0 == 0)  ? 2  : 0;
    int rhi2 = (!odd && oy0 == 80) ? 18 : 20;
    int clo2 = (!odd && ox0 == 0)  ? 2  : 0;
    int chi2 = (!odd && ox0 == 64) ? 34 : 36;

#pragma unroll
    for (int jj = 0; jj < 3; jj++) {
        if (q_[jj] < 720) {
            bool valid = (row2_[jj] >= rlo2) && (row2_[jj] < rhi2) &&
                         (col2_[jj] >= clo2) && (col2_[jj] < chi2);
#pragma unroll
            for (int cf = 0; cf < 2; cf++)
#pragma unroll
                for (int rb = 0; rb < 4; rb++) {
                    float v0 = 0.f, v1 = 0.f, v2 = 0.f, v3 = 0.f;
                    if (valid) {
                        float4 bb = *(const float4*)(biasg + 64 + 32 * cf + 8 * rb + 4 * kq);
                        v0 = fmaxf(acc2[jj][cf][rb * 4 + 0] + bb.x, 0.f);
                        v1 = fmaxf(acc2[jj][cf][rb * 4 + 1] + bb.y, 0.f);
                        v2 = fmaxf(acc2[jj][cf][rb * 4 + 2] + bb.z, 0.f);
                        v3 = fmaxf(acc2[jj][cf][rb * 4 + 3] + bb.w, 0.f);
                    }
                    uint2 pk = make_uint2((unsigned)f2bf(v0) | ((unsigned)f2bf(v1) << 16),
                                          (unsigned)f2bf(v2) | ((unsigned)f2bf(v3) << 16));
                    *(uint2*)(c2out + q_[jj] * 68 + 32 * cf + 8 * rb + 4 * kq) = pk;
                }
        }
    }
    __syncthreads();

    // ---- conv3 from c2out; wave owns out rows {2wv, 2wv+1} x 32 cols ----
    floatx16 acc3[2][2];   // [cf][pf]
#pragma unroll
    for (int cf = 0; cf < 2; cf++)
#pragma unroll
        for (int pf = 0; pf < 2; pf++)
#pragma unroll
            for (int i = 0; i < 16; i++) acc3[cf][pf][i] = 0.f;

#pragma unroll
    for (int ks = 0; ks < 4; ks++) {
#pragma unroll
        for (int tb = 0; tb < 3; tb++) {
            short8 a[3][2];
#pragma unroll
            for (int ta = 0; ta < 3; ta++)
#pragma unroll
                for (int cf = 0; cf < 2; cf++)
                    a[ta][cf] = A3[(((ta * 3 + tb) * 4 + ks) * 2 + cf) * 64 + lane];
            int col = n + 2 * tb;
            int uoff = (2 * ks + kq) << 3;   // ci block within 64
            short8 bf[6];
#pragma unroll
            for (int rr = 0; rr < 6; rr++) {
                int q = (2 * wv + rr) * 36 + col;
                bf[rr] = *(const short8*)(c2out + q * 68 + uoff);
            }
#pragma unroll
            for (int ta = 0; ta < 3; ta++)
#pragma unroll
                for (int pf = 0; pf < 2; pf++) {
                    int rr = pf + 2 * ta;
                    acc3[0][pf] = __builtin_amdgcn_mfma_f32_32x32x16_bf16(a[ta][0], bf[rr], acc3[0][pf], 0, 0, 0);
                    acc3[1][pf] = __builtin_amdgcn_mfma_f32_32x32x16_bf16(a[ta][1], bf[rr], acc3[1][pf], 0, 0, 0);
                }
        }
    }

    // epilogue: bias + relu + max over 64 co -> maxb
#pragma unroll
    for (int pf = 0; pf < 2; pf++) {
        float m = 0.f;
#pragma unroll
        for (int cf = 0; cf < 2; cf++)
#pragma unroll
            for (int rb = 0; rb < 4; rb++) {
                float4 bb = *(const float4*)(biasg + 128 + 32 * cf + 8 * rb + 4 * kq);
                m = fmaxf(m, acc3[cf][pf][rb * 4 + 0] + bb.x);
                m = fmaxf(m, acc3[cf][pf][rb * 4 + 1] + bb.y);
                m = fmaxf(m, acc3[cf][pf][rb * 4 + 2] + bb.z);
                m = fmaxf(m, acc3[cf][pf][rb * 4 + 3] + bb.w);
            }
        m = fmaxf(m, 0.f);
        m = fmaxf(m, __shfl_xor(m, 32, 64));
        if (lane < 32)
            maxb[((size_t)z * 96 + oy0 + 2 * wv + pf) * 96 + ox0 + n] = m;
    }
}

__global__ void final_k(const float* __restrict__ maxb, float* __restrict__ out) {
    int i = blockIdx.x * 256 + threadIdx.x;
    if (i < B * HW * HW) {
        int b = i / 9216, yx = i - b * 9216;
        float m = 0.f;
#pragma unroll
        for (int br = 0; br < 8; br++)
            m = fmaxf(m, maxb[((size_t)(br * 8 + b)) * 9216 + yx]);
        float v = 1.f / (1.f + expf(-m));
        out[i] = fminf(fmaxf(v, 1e-4f), 1.f - 1e-4f);
    }
}

// ---------------- launch ----------------

extern "C" void kernel_launch(void* const* d_in, const int* in_sizes, int n_in,
                              void* d_out, int out_size, void* d_ws, size_t ws_size,
                              hipStream_t stream) {
    const float* x     = (const float*)d_in[0];
    const float* dcn_w = (const float*)d_in[2];
    const float* dcn_b = (const float*)d_in[3];
    const float* c2w   = (const float*)d_in[4];
    const float* c2b   = (const float*)d_in[5];
    const float* c3w   = (const float*)d_in[6];
    const float* c3b   = (const float*)d_in[7];
    const float* gamma = (const float*)d_in[8];
    const float* beta  = (const float*)d_in[9];
    const float* mean  = (const float*)d_in[10];
    const float* var_  = (const float*)d_in[11];

    char* ws = (char*)d_ws;
    unsigned short* Wall = (unsigned short*)ws;                       // 1.18 MB
    size_t off = (size_t)16 * NWV * 2;
    float* biasg = (float*)(ws + off);            off += 1024;
    float* maxb  = (float*)(ws + off);            off += (size_t)64 * 9216 * 4;        // 2.36 MB
    unsigned short* xhwc = (unsigned short*)(ws + off); off += (size_t)B * 9216 * 64 * 2;    // 9.4 MB
    unsigned short* buf1 = (unsigned short*)(ws + off);                                 // 88.6 MB framed

    prep_w<<<(16 * NWV + 255) / 256, 256, 0, stream>>>(dcn_w, c2w, c3w, gamma, var_, Wall);
    prep_bias<<<1, 256, 0, stream>>>(dcn_b, c2b, c3b, gamma, beta, mean, var_, biasg);
    prep_x<<<B * 96, 256, 0, stream>>>(x, xhwc);
    border_clear<<<dim3(50, 32), 256, 0, stream>>>(buf1);

    dim3 g1(4, 7, 64);
    conv1_k<<<g1, 512, 0, stream>>>(xhwc, buf1, Wall, biasg);

    dim3 g23(3, 6, 64);
    conv23_k<<<g23, 512, 0, stream>>>(buf1, maxb, Wall, biasg);

    final_k<<<(B * HW * HW + 255) / 256, 256, 0, stream>>>(maxb, (float*)d_out);
}